// Round 5
// baseline (413.229 us; speedup 1.0000x reference)
//
#include <hip/hip_runtime.h>

// EdgeFormerINT4Linear via INT8 dynamic quantization:
// y[m,o] = (sum_i xq[m,i]*q[o,i]) * (srow[m]*scale[o]) + bias[o]
// Round 6: R0 gemm geometry restored EXACTLY (128x128 tile, 4 waves, single
// buffer, 2-barrier K-loop, NATURAL block order — R4 proved the natural
// dispatch gives each XCD a fixed 4-N-panel set (n === c mod 8), 2MB of B
// L2-resident; any M-grouping swizzle thrashes L2: FETCH 171->383MB, +20us).
// One change inside the verified structure: MFMA 16x16x64 -> 32x32x32 i8
// (+12% pipe ceiling 3944->4404 TOPS, half the MFMA instruction count).
// Read geometry generalizes the verified pattern: row = lane&31 (was &15),
// chunk-group = lane>>5 (was >>4), same 16B XOR-swizzled slots -> same
// conflict-free condition. 32x32 C/D layout (col=lane&31,
// row=(reg&3)+8*(reg>>2)+4*(lane>>5)) is HW-verified dtype-independent.

#define M_ROWS 8192
#define N_COLS 4096
#define K_DIM  4096

typedef int int32x4  __attribute__((ext_vector_type(4)));
typedef int int32x16 __attribute__((ext_vector_type(16)));

__device__ __forceinline__ void async16(const void* g, void* l) {
  __builtin_amdgcn_global_load_lds(
      (const __attribute__((address_space(1))) void*)g,
      (__attribute__((address_space(3))) void*)l,
      16 /*bytes*/, 0 /*offset*/, 0 /*aux*/);
}

// ---- fused prepass ----
// blocks [0, M_ROWS): per-row symmetric int8 quant of x (256 thr x 16 elems)
// blocks [M_ROWS, ...): q int32 -> int8 pack (1 int4/thread)
__global__ __launch_bounds__(256) void prep_kernel(const float4* __restrict__ x,
                                                   int* __restrict__ xq,
                                                   float* __restrict__ srow,
                                                   const int4* __restrict__ q,
                                                   int* __restrict__ q8) {
  const int t = threadIdx.x;
  if (blockIdx.x >= M_ROWS) {
    const int i = (blockIdx.x - M_ROWS) * 256 + t;
    const int4 v = q[i];
    q8[i] = (v.x & 0xff) | ((v.y & 0xff) << 8) | ((v.z & 0xff) << 16) | (v.w << 24);
    return;
  }
  const int row = blockIdx.x;
  const float4* xr = x + (size_t)row * (K_DIM / 4);
  float4 v[4];
  float am = 0.f;
#pragma unroll
  for (int j = 0; j < 4; ++j) {
    v[j] = xr[t + 256 * j];
    am = fmaxf(am, fmaxf(fmaxf(fabsf(v[j].x), fabsf(v[j].y)),
                         fmaxf(fabsf(v[j].z), fabsf(v[j].w))));
  }
#pragma unroll
  for (int off = 32; off > 0; off >>= 1)
    am = fmaxf(am, __shfl_down(am, off, 64));
  __shared__ float wmax[4];
  if ((t & 63) == 0) wmax[t >> 6] = am;
  __syncthreads();
  am = fmaxf(fmaxf(wmax[0], wmax[1]), fmaxf(wmax[2], wmax[3]));
  const float s   = am * (1.f / 127.f);
  const float inv = (am > 0.f) ? 127.f / am : 0.f;
  if (t == 0) srow[row] = s;
  int* o = xq + (size_t)row * (K_DIM / 4);
#pragma unroll
  for (int j = 0; j < 4; ++j) {
    int a = __float2int_rn(v[j].x * inv);
    int b = __float2int_rn(v[j].y * inv);
    int c = __float2int_rn(v[j].z * inv);
    int d = __float2int_rn(v[j].w * inv);
    o[t + 256 * j] = (a & 0xff) | ((b & 0xff) << 8) | ((c & 0xff) << 16) | (d << 24);
  }
}

// ---- GEMM: A[M,K] int8 row-major, B[N,K] int8 row-major (B^T form) ----
// Block = 256 threads (4 waves), tile 128x128, BK=128 B. Each wave: 2x2 grid
// of 32x32x32 i8 MFMAs, 4 K-steps per tile. Natural block order (no swizzle).
__global__ __launch_bounds__(256, 4) void gemm_i8_kernel(
    const char* __restrict__ A, const char* __restrict__ B,
    const float* __restrict__ scale, const float* __restrict__ srow,
    const float* __restrict__ bias, float* __restrict__ out) {
  __shared__ __attribute__((aligned(16))) char sA[128 * 128];
  __shared__ __attribute__((aligned(16))) char sB[128 * 128];

  const int tid  = threadIdx.x;
  const int lane = tid & 63;
  const int w    = tid >> 6;
  const int wr   = w >> 1;      // M half of tile
  const int wc   = w & 1;       // N half of tile
  const int l31  = lane & 31;   // fragment row (A: m, B: n, C: col/n)
  const int lh   = lane >> 5;   // k-chunk group 0..1
  const int kx   = l31 & 7;     // XOR term (row&7) for all fragment rows

  const int m0 = blockIdx.y * 128;
  const int n0 = blockIdx.x * 128;

  int32x16 acc[2][2];
#pragma unroll
  for (int i = 0; i < 2; ++i)
#pragma unroll
    for (int j = 0; j < 2; ++j)
      acc[i][j] = (int32x16){0};

  for (int it = 0; it < K_DIM / 128; ++it) {
    const int k0 = it * 128;   // byte offset within a row (1 int8 = 1 byte)
#pragma unroll
    for (int i = 0; i < 4; ++i) {
      const int ch = i * 256 + tid;          // chunk 0..1023
      const int r  = ch >> 3;                // tile row 0..127
      const int sc = (ch & 7) ^ (r & 7);     // swizzled source col-chunk
      async16(A + (size_t)(m0 + r) * K_DIM + k0 + sc * 16, sA + ch * 16);
      async16(B + (size_t)(n0 + r) * K_DIM + k0 + sc * 16, sB + ch * 16);
    }
    __syncthreads();

#pragma unroll
    for (int kk = 0; kk < 4; ++kk) {
      const int slot = (kk * 2 + lh) ^ kx;   // global chunk kk*2+lh, unswizzled
      int32x4 af[2], bf[2];
#pragma unroll
      for (int mi = 0; mi < 2; ++mi) {
        const int row = wr * 64 + mi * 32 + l31;
        af[mi] = *(const int32x4*)(sA + (row * 8 + slot) * 16);
      }
#pragma unroll
      for (int nj = 0; nj < 2; ++nj) {
        const int row = wc * 64 + nj * 32 + l31;
        bf[nj] = *(const int32x4*)(sB + (row * 8 + slot) * 16);
      }
#pragma unroll
      for (int mi = 0; mi < 2; ++mi)
#pragma unroll
        for (int nj = 0; nj < 2; ++nj)
          acc[mi][nj] = __builtin_amdgcn_mfma_i32_32x32x32_i8(af[mi], bf[nj],
                                                              acc[mi][nj], 0, 0, 0);
    }
    __syncthreads();
  }

  // epilogue: 32x32 C/D layout col=lane&31 (n), row=(reg&3)+8*(reg>>2)+4*lh (m)
#pragma unroll
  for (int nj = 0; nj < 2; ++nj) {
    const int o    = n0 + wc * 64 + nj * 32 + l31;
    const float so = scale[o];
    const float bz = bias[o];
#pragma unroll
    for (int mi = 0; mi < 2; ++mi) {
      const int mbase = m0 + wr * 64 + mi * 32 + lh * 4;
#pragma unroll
      for (int r = 0; r < 16; ++r) {
        const int m = mbase + (r & 3) + 8 * (r >> 2);
        out[(size_t)m * N_COLS + o] = (float)acc[mi][nj][r] * (so * srow[m]) + bz;
      }
    }
  }
}

extern "C" void kernel_launch(void* const* d_in, const int* in_sizes, int n_in,
                              void* d_out, int out_size, void* d_ws, size_t ws_size,
                              hipStream_t stream) {
  const float* x     = (const float*)d_in[0];   // [4,2048,4096] fp32
  const int*   q     = (const int*)d_in[1];     // [4096,4096] int32 in [-8,7]
  const float* scale = (const float*)d_in[2];   // [4096]
  const float* bias  = (const float*)d_in[3];   // [4096]
  float* out = (float*)d_out;                   // [8192,4096] fp32

  // workspace: A8 (32 MiB) | B8 (16 MiB) | srow (32 KiB)
  char*  A8   = (char*)d_ws;
  char*  B8   = (char*)d_ws + (size_t)M_ROWS * K_DIM;
  float* srow = (float*)((char*)B8 + (size_t)N_COLS * K_DIM);

  const int cvt_blocks = (N_COLS * K_DIM / 4) / 256;   // 16384
  prep_kernel<<<M_ROWS + cvt_blocks, 256, 0, stream>>>(
      (const float4*)x, (int*)A8, srow, (const int4*)q, (int*)B8);

  dim3 grid(N_COLS / 128, M_ROWS / 128);  // 32 x 64 = 2048 blocks
  gemm_i8_kernel<<<grid, 256, 0, stream>>>(A8, B8, scale, srow, bias, out);
}